// Round 4
// baseline (165.226 us; speedup 1.0000x reference)
//
#include <hip/hip_runtime.h>
#include <hip/hip_bf16.h>

// OptimizedISM: D [4,256,32,32] f32, S [4,256,64,64] f32 -> Z [4,256,64,64] f32
// Z[b,c,h,w] = sum_{i,j} softmax_j(Q[b,:,h,w]·S[b,:,i,j]/16) * S[b,c,i,j] + Q[b,c,h,w]
// Q = nearest-upsample(D): 1024 distinct queries/batch.
// Phase A: P = softmax(Q K^T) [128x128 tiles]; Phase B: Z = P V (128x128, K-split 8).

typedef __attribute__((ext_vector_type(8))) short bf16x8;
typedef __attribute__((ext_vector_type(4))) float f32x4;
typedef __attribute__((ext_vector_type(2))) float f32x2;

#define MFMA16(a, b, c) __builtin_amdgcn_mfma_f32_16x16x32_bf16(a, b, c, 0, 0, 0)

__device__ __forceinline__ unsigned short f2bf(float v) {
    union { __hip_bfloat16 h; unsigned short u; } cv;
    cv.h = __float2bfloat16(v);
    return cv.u;
}

// async global->LDS, 16B/lane; dest must be wave-uniform base + lane*16 (linear).
__device__ __forceinline__ void gl_lds16(const unsigned short* g, unsigned short* l) {
    __builtin_amdgcn_global_load_lds(
        (const __attribute__((address_space(1))) unsigned int*)g,
        (__attribute__((address_space(3))) unsigned int*)l, 16, 0, 0);
}

// Stage a [128 rows][64 cols] bf16 tile into linear LDS [128][64], source
// XOR-swizzled (chunk c8 <- global chunk c8^(row&7)) so swizzled ds_read_b128
// is bank-conflict-free. 4 issues/thread.
__device__ __forceinline__ void stage_tile(
    const unsigned short* __restrict__ g, unsigned short* l,
    int gstride, int k0, int wid, int lane)
{
    const int r8 = lane >> 3;   // 0..7
    const int c8 = lane & 7;    // 16B chunk within 128B row
    const int scc = c8 ^ r8;    // row&7 == r8 for all staged rows
#pragma unroll
    for (int i = 0; i < 4; ++i) {
        const int row = i * 32 + wid * 8 + r8;
        gl_lds16(g + (size_t)row * gstride + k0 + scc * 8, l + row * 64 + c8 * 8);
    }
}

// One BK=64 step of the 64x64 per-wave quadrant: 16 ds_read_b128 + 32 MFMA.
__device__ __forceinline__ void gemm_step(
    const unsigned short* al, const unsigned short* bl,
    f32x4 z[4][4], int lrow, int lgrp)
{
    const int swz = lrow & 7;
#pragma unroll
    for (int kk = 0; kk < 2; ++kk) {
        bf16x8 am[4], bn[4];
        const int ch = ((kk * 4 + lgrp) ^ swz) * 8;
#pragma unroll
        for (int m = 0; m < 4; ++m) am[m] = *(const bf16x8*)&al[(m * 16 + lrow) * 64 + ch];
#pragma unroll
        for (int n = 0; n < 4; ++n) bn[n] = *(const bf16x8*)&bl[(n * 16 + lrow) * 64 + ch];
#pragma unroll
        for (int m = 0; m < 4; ++m)
#pragma unroll
            for (int n = 0; n < 4; ++n) z[m][n] = MFMA16(am[m], bn[n], z[m][n]);
    }
}

// ---------------------------------------------------------------------------
// Prep: fp32 [B][256][ncols] -> bf16 transposed [B][ncols][256] (outT)
// and optionally same-layout bf16 copy (outC).
// ---------------------------------------------------------------------------
__global__ __launch_bounds__(256) void cvt_transpose(
    const float* __restrict__ in, unsigned short* __restrict__ outT,
    unsigned short* __restrict__ outC, int ncols)
{
    __shared__ float tile[32][33];
    const int bz = blockIdx.z;
    const int p0 = blockIdx.x << 5;
    const int c0 = blockIdx.y << 5;
    const int tx = threadIdx.x & 31;
    const int ty = threadIdx.x >> 5;

    const float* src = in + ((size_t)bz * 256 + c0) * ncols + p0;
#pragma unroll
    for (int k = 0; k < 4; ++k) {
        const int cc = ty + (k << 3);
        float v = src[(size_t)cc * ncols + tx];
        tile[cc][tx] = v;
        if (outC) outC[((size_t)bz * 256 + (c0 + cc)) * ncols + p0 + tx] = f2bf(v);
    }
    __syncthreads();
    unsigned short* dst = outT + ((size_t)bz * ncols + p0) * 256 + c0;
#pragma unroll
    for (int k = 0; k < 4; ++k) {
        const int pp = ty + (k << 3);
        dst[(size_t)pp * 256 + tx] = f2bf(tile[tx][pp]);
    }
}

// ---------------------------------------------------------------------------
// Phase A: P[b][q][ij] = softmax_j(Q·K^T / 16), bf16. Tile 128q x 128j,
// K=256 (4 steps, single-buffer LDS, 2 barriers/step, 4 blocks/CU).
// Wave quadrant 64q x 64j = exactly one softmax group in j.
// ---------------------------------------------------------------------------
__global__ __launch_bounds__(256, 4) void ism_qk(
    const unsigned short* __restrict__ Kt,  // [4][4096][256] bf16
    const unsigned short* __restrict__ Qb,  // [4][1024][256] bf16
    unsigned short* __restrict__ P)         // [4][1024][4096] bf16
{
    __shared__ unsigned short alds[128 * 64]; // 16 KB (Q tile chunk)
    __shared__ unsigned short blds[128 * 64]; // 16 KB (K tile chunk)

    const int tid = threadIdx.x;
    const int wid = tid >> 6;
    const int lane = tid & 63;
    const int lrow = lane & 15;
    const int lgrp = lane >> 4;
    const int wr = wid >> 1;  // quadrant row
    const int wc = wid & 1;   // quadrant col

    const int blk = blockIdx.x;             // 1024 = 8 xcd * 128
    const int xcd = blk & 7;
    const int b = xcd >> 1;
    const int sub = blk >> 3;               // 0..127
    const int qt = sub & 7;                 // 8 q-tiles
    const int jt = (sub >> 3) | ((xcd & 1) << 4);  // 0..31 j-tiles

    const unsigned short* ag = Qb + ((size_t)b * 1024 + qt * 128) * 256;
    const unsigned short* bg = Kt + ((size_t)b * 4096 + jt * 128) * 256;

    const f32x4 fzero = {0.f, 0.f, 0.f, 0.f};
    f32x4 z[4][4];
#pragma unroll
    for (int m = 0; m < 4; ++m)
#pragma unroll
        for (int n = 0; n < 4; ++n) z[m][n] = fzero;

#pragma unroll 1
    for (int s = 0; s < 4; ++s) {
        stage_tile(ag, alds, 256, s * 64, wid, lane);
        stage_tile(bg, blds, 256, s * 64, wid, lane);
        __syncthreads();
        gemm_step(&alds[wr * 4096], &blds[wc * 4096], z, lrow, lgrp);
        __syncthreads();
    }

    // ---- softmax over j (per wave-quadrant row: 4 n-regs x 16 lrow lanes) ----
    const float SC = 0.09016844f; // log2(e)/16
    unsigned short* pb = P + ((size_t)b * 1024 + qt * 128 + wr * 64) * 4096
                       + (size_t)jt * 128 + wc * 64;
#pragma unroll
    for (int m = 0; m < 4; ++m) {
        float mr[4], sm[4];
#pragma unroll
        for (int r = 0; r < 4; ++r) {
            float m0 = fmaxf(fmaxf(z[m][0][r], z[m][1][r]), fmaxf(z[m][2][r], z[m][3][r]));
            m0 = fmaxf(m0, __shfl_xor(m0, 1));
            m0 = fmaxf(m0, __shfl_xor(m0, 2));
            m0 = fmaxf(m0, __shfl_xor(m0, 4));
            m0 = fmaxf(m0, __shfl_xor(m0, 8));
            mr[r] = m0;
            sm[r] = 0.f;
        }
#pragma unroll
        for (int n = 0; n < 4; ++n)
#pragma unroll
            for (int r = 0; r < 4; ++r) {
                float p = exp2f((z[m][n][r] - mr[r]) * SC);
                z[m][n][r] = p;
                sm[r] += p;
            }
#pragma unroll
        for (int r = 0; r < 4; ++r) {
            float t = sm[r];
            t += __shfl_xor(t, 1);
            t += __shfl_xor(t, 2);
            t += __shfl_xor(t, 4);
            t += __shfl_xor(t, 8);
            sm[r] = 1.0f / t;
        }
#pragma unroll
        for (int n = 0; n < 4; ++n)
#pragma unroll
            for (int r = 0; r < 4; ++r)
                pb[(size_t)(m * 16 + (lgrp << 2) + r) * 4096 + n * 16 + lrow]
                    = f2bf(z[m][n][r] * sm[r]);
    }
}

// ---------------------------------------------------------------------------
// Phase B: acc[b][c][q] += P[q][ij] · V[c][ij]. Tile 128q x 128c, K-split 8
// (K=512/block, 8 steps of 64). Double-buffered LDS (64 KB, 2 blocks/CU),
// STAGE-early + one barrier/step. f32 atomicAdd epilogue.
// ---------------------------------------------------------------------------
__global__ __launch_bounds__(256, 2) void ism_pv(
    const unsigned short* __restrict__ P,   // [4][1024][4096] bf16
    const unsigned short* __restrict__ Vt,  // [4][256][4096] bf16
    float* __restrict__ acc)                // [4][256][1024] f32 (zeroed)
{
    __shared__ unsigned short alds[2][128 * 64]; // 2 x 16 KB
    __shared__ unsigned short blds[2][128 * 64]; // 2 x 16 KB

    const int tid = threadIdx.x;
    const int wid = tid >> 6;
    const int lane = tid & 63;
    const int lrow = lane & 15;
    const int lgrp = lane >> 4;
    const int wr = wid >> 1;
    const int wc = wid & 1;

    const int blk = blockIdx.x;             // 512 = 8 xcd * 64
    const int xcd = blk & 7;
    const int b = xcd >> 1;
    const int sub = blk >> 3;               // 0..63
    const int qt = sub & 7;                 // 8 q-tiles
    const int ct = (sub >> 3) & 1;          // 2 c-tiles
    const int ks = (sub >> 4) | ((xcd & 1) << 2);  // 0..7 K-split

    const unsigned short* ag = P + ((size_t)b * 1024 + qt * 128) * 4096 + (size_t)ks * 512;
    const unsigned short* bg = Vt + ((size_t)b * 256 + ct * 128) * 4096 + (size_t)ks * 512;

    const f32x4 fzero = {0.f, 0.f, 0.f, 0.f};
    f32x4 z[4][4];
#pragma unroll
    for (int m = 0; m < 4; ++m)
#pragma unroll
        for (int n = 0; n < 4; ++n) z[m][n] = fzero;

    stage_tile(ag, alds[0], 4096, 0, wid, lane);
    stage_tile(bg, blds[0], 4096, 0, wid, lane);
    __syncthreads();

#pragma unroll 1
    for (int s = 0; s < 8; ++s) {
        const int cur = s & 1;
        if (s < 7) {
            stage_tile(ag, alds[cur ^ 1], 4096, (s + 1) * 64, wid, lane);
            stage_tile(bg, blds[cur ^ 1], 4096, (s + 1) * 64, wid, lane);
        }
        gemm_step(&alds[cur][wr * 4096], &blds[cur][wc * 4096], z, lrow, lgrp);
        __syncthreads();
    }

    // ---- epilogue: z[m][n][r] = Z[q=wr*64+m*16+4lgrp+r][c=wc*64+n*16+lrow] ----
    float* ab = acc + ((size_t)b * 256 + ct * 128 + wc * 64) * 1024 + qt * 128 + wr * 64;
#pragma unroll
    for (int m = 0; m < 4; ++m)
#pragma unroll
        for (int n = 0; n < 4; ++n)
#pragma unroll
            for (int r = 0; r < 4; ++r)
                atomicAdd(ab + (size_t)(n * 16 + lrow) * 1024 + m * 16 + (lgrp << 2) + r,
                          z[m][n][r]);
}

// ---------------------------------------------------------------------------
// Reduce: Z = acc + D (exact f32 residual), 2x2 nearest-upsample duplication.
// ---------------------------------------------------------------------------
__global__ __launch_bounds__(256) void ism_red(
    const float* __restrict__ acc, const float* __restrict__ D, float* __restrict__ Z)
{
    const int blk = blockIdx.x;             // 8192 = 8 xcd * 1024
    const int xcd = blk & 7;
    const int b = xcd >> 1;
    const int lin = (blk >> 3) * 256 + threadIdx.x;  // 0..262143
    const int q0 = (lin & 511) << 1;
    const int c = ((lin >> 9) & 127) | ((xcd & 1) << 7);

    const size_t base = ((size_t)b * 256 + c) * 1024 + q0;
    f32x2 d = *(const f32x2*)(D + base);
    f32x2 a = *(const f32x2*)(acc + base);
    const float v0 = d[0] + a[0];
    const float v1 = d[1] + a[1];

    const int qh = q0 >> 5, qw = q0 & 31;
    float* o = Z + (((size_t)b * 256 + c) * 64 + qh * 2) * 64 + qw * 2;
    f32x4 val = {v0, v0, v1, v1};
    *(f32x4*)o = val;
    *(f32x4*)(o + 64) = val;
}

// ---------------------------------------------------------------------------
extern "C" void kernel_launch(void* const* d_in, const int* in_sizes, int n_in,
                              void* d_out, int out_size, void* d_ws, size_t ws_size,
                              hipStream_t stream)
{
    const float* D = (const float*)d_in[0];  // [4,256,32,32]
    const float* S = (const float*)d_in[1];  // [4,256,64,64]
    float* Z = (float*)d_out;

    // ws layout (50 MiB, proven available):
    //  [0,8M)    Kt [4][4096][256] bf16  (dead after ism_qk; acc f32 4MB overlays)
    //  [8,10M)   Qb [4][1024][256] bf16  (dead after ism_qk)
    //  [10,42M)  P  [4][1024][4096] bf16
    //  [42,50M)  Vt [4][256][4096] bf16
    char* ws = (char*)d_ws;
    unsigned short* Kt = (unsigned short*)ws;
    unsigned short* Qb = (unsigned short*)(ws + 8388608);
    unsigned short* P  = (unsigned short*)(ws + 10485760);
    unsigned short* Vt = (unsigned short*)(ws + 44040192);
    float* acc = (float*)ws;

    cvt_transpose<<<dim3(128, 8, 4), 256, 0, stream>>>(S, Kt, Vt, 4096);
    cvt_transpose<<<dim3(32, 8, 4), 256, 0, stream>>>(D, Qb, nullptr, 1024);

    ism_qk<<<1024, 256, 0, stream>>>(Kt, Qb, P);

    hipMemsetAsync(acc, 0, (size_t)4 * 256 * 1024 * 4, stream);

    ism_pv<<<512, 256, 0, stream>>>(P, Vt, acc);
    ism_red<<<8192, 256, 0, stream>>>(acc, D, Z);
}

// Round 5
// 60.460 us; speedup vs baseline: 2.7328x; 2.7328x over previous
//
#include <hip/hip_runtime.h>
#include <hip/hip_bf16.h>

// OptimizedISM: D [4,256,32,32] f32, S [4,256,64,64] f32 -> Z [4,256,64,64] f32
// Z[b,c,h,w] = sum_{i,j} softmax_j(Q[b,:,h,w]·S[b,:,i,j]/16) * S[b,c,i,j] + Q[b,c,h,w]
// Q = nearest-upsample(D): 1024 distinct queries/batch.
// Phase A: P = softmax(Q K^T) (128x128 tiles, LDS-coalesced store).
// Phase B: partial[ks] = P·V (128x128, K-split 4, f16 partials, NO atomics).
// Reduce: Z = sum_ks partial + D, 2x2 duplicated.

typedef __attribute__((ext_vector_type(8))) short bf16x8;
typedef __attribute__((ext_vector_type(4))) float f32x4;
typedef __attribute__((ext_vector_type(2))) float f32x2;
typedef _Float16 f16;
typedef __attribute__((ext_vector_type(2))) _Float16 f16x2;

#define MFMA16(a, b, c) __builtin_amdgcn_mfma_f32_16x16x32_bf16(a, b, c, 0, 0, 0)

__device__ __forceinline__ unsigned short f2bf(float v) {
    union { __hip_bfloat16 h; unsigned short u; } cv;
    cv.h = __float2bfloat16(v);
    return cv.u;
}

// async global->LDS, 16B/lane; dest = wave-uniform base + lane*16 (linear).
__device__ __forceinline__ void gl_lds16(const unsigned short* g, unsigned short* l) {
    __builtin_amdgcn_global_load_lds(
        (const __attribute__((address_space(1))) unsigned int*)g,
        (__attribute__((address_space(3))) unsigned int*)l, 16, 0, 0);
}

// Stage a [128 rows][64 cols] bf16 tile into linear LDS [128][64], source
// XOR-swizzled (chunk c8 <- global chunk c8^(row&7)) so swizzled ds_read_b128
// is bank-conflict-free (0 conflicts measured R3/R4). 4 issues/thread.
__device__ __forceinline__ void stage_tile(
    const unsigned short* __restrict__ g, unsigned short* l,
    int gstride, int k0, int wid, int lane)
{
    const int r8 = lane >> 3;
    const int c8 = lane & 7;
    const int scc = c8 ^ r8;
#pragma unroll
    for (int i = 0; i < 4; ++i) {
        const int row = i * 32 + wid * 8 + r8;
        gl_lds16(g + (size_t)row * gstride + k0 + scc * 8, l + row * 64 + c8 * 8);
    }
}

// One BK=64 step of the 64x64 per-wave quadrant: 16 ds_read_b128 + 32 MFMA.
__device__ __forceinline__ void gemm_step(
    const unsigned short* al, const unsigned short* bl,
    f32x4 z[4][4], int lrow, int lgrp)
{
    const int swz = lrow & 7;
#pragma unroll
    for (int kk = 0; kk < 2; ++kk) {
        bf16x8 am[4], bn[4];
        const int ch = ((kk * 4 + lgrp) ^ swz) * 8;
#pragma unroll
        for (int m = 0; m < 4; ++m) am[m] = *(const bf16x8*)&al[(m * 16 + lrow) * 64 + ch];
#pragma unroll
        for (int n = 0; n < 4; ++n) bn[n] = *(const bf16x8*)&bl[(n * 16 + lrow) * 64 + ch];
#pragma unroll
        for (int m = 0; m < 4; ++m)
#pragma unroll
            for (int n = 0; n < 4; ++n) z[m][n] = MFMA16(am[m], bn[n], z[m][n]);
    }
}

// ---------------------------------------------------------------------------
// Prep: fp32 [B][256][ncols] -> bf16 transposed [B][ncols][256] (outT)
// and optionally same-layout bf16 copy (outC).
// ---------------------------------------------------------------------------
__global__ __launch_bounds__(256) void cvt_transpose(
    const float* __restrict__ in, unsigned short* __restrict__ outT,
    unsigned short* __restrict__ outC, int ncols)
{
    __shared__ float tile[32][33];
    const int bz = blockIdx.z;
    const int p0 = blockIdx.x << 5;
    const int c0 = blockIdx.y << 5;
    const int tx = threadIdx.x & 31;
    const int ty = threadIdx.x >> 5;

    const float* src = in + ((size_t)bz * 256 + c0) * ncols + p0;
#pragma unroll
    for (int k = 0; k < 4; ++k) {
        const int cc = ty + (k << 3);
        float v = src[(size_t)cc * ncols + tx];
        tile[cc][tx] = v;
        if (outC) outC[((size_t)bz * 256 + (c0 + cc)) * ncols + p0 + tx] = f2bf(v);
    }
    __syncthreads();
    unsigned short* dst = outT + ((size_t)bz * ncols + p0) * 256 + c0;
#pragma unroll
    for (int k = 0; k < 4; ++k) {
        const int pp = ty + (k << 3);
        dst[(size_t)pp * 256 + tx] = f2bf(tile[tx][pp]);
    }
}

// ---------------------------------------------------------------------------
// Phase A: P[b][q][ij] = softmax_j(Q·K^T / 16), bf16. Tile 128q x 128j,
// K=256 (4 steps, single-buffer LDS). Wave quadrant 64q x 64j = one j-group.
// P tile staged in LDS then written out with coalesced 16B stores.
// ---------------------------------------------------------------------------
__global__ __launch_bounds__(256, 4) void ism_qk(
    const unsigned short* __restrict__ Kt,  // [4][4096][256] bf16
    const unsigned short* __restrict__ Qb,  // [4][1024][256] bf16
    unsigned short* __restrict__ P)         // [4][1024][4096] bf16
{
    __shared__ unsigned short smem[17408];  // 34.8 KB: stage (32 KB) | P-tile [128][136]
    unsigned short* alds = smem;            // [128][64]
    unsigned short* blds = smem + 8192;     // [128][64]

    const int tid = threadIdx.x;
    const int wid = tid >> 6;
    const int lane = tid & 63;
    const int lrow = lane & 15;
    const int lgrp = lane >> 4;
    const int wr = wid >> 1;
    const int wc = wid & 1;

    const int blk = blockIdx.x;             // 1024 = 8 xcd * 128
    const int xcd = blk & 7;
    const int b = xcd >> 1;
    const int sub = blk >> 3;
    const int qt = sub & 7;
    const int jt = (sub >> 3) | ((xcd & 1) << 4);  // 0..31 j-tiles (128 wide)

    const unsigned short* ag = Qb + ((size_t)b * 1024 + qt * 128) * 256;
    const unsigned short* bg = Kt + ((size_t)b * 4096 + jt * 128) * 256;

    const f32x4 fzero = {0.f, 0.f, 0.f, 0.f};
    f32x4 z[4][4];
#pragma unroll
    for (int m = 0; m < 4; ++m)
#pragma unroll
        for (int n = 0; n < 4; ++n) z[m][n] = fzero;

#pragma unroll 1
    for (int s = 0; s < 4; ++s) {
        stage_tile(ag, alds, 256, s * 64, wid, lane);
        stage_tile(bg, blds, 256, s * 64, wid, lane);
        __syncthreads();
        gemm_step(&alds[wr * 4096], &blds[wc * 4096], z, lrow, lgrp);
        __syncthreads();
    }

    // ---- softmax over j within wave quadrant (j-group = 64) ----
    const float SC = 0.09016844f; // log2(e)/16
#pragma unroll
    for (int m = 0; m < 4; ++m) {
        float mr[4], sm[4];
#pragma unroll
        for (int r = 0; r < 4; ++r) {
            float m0 = fmaxf(fmaxf(z[m][0][r], z[m][1][r]), fmaxf(z[m][2][r], z[m][3][r]));
            m0 = fmaxf(m0, __shfl_xor(m0, 1));
            m0 = fmaxf(m0, __shfl_xor(m0, 2));
            m0 = fmaxf(m0, __shfl_xor(m0, 4));
            m0 = fmaxf(m0, __shfl_xor(m0, 8));
            mr[r] = m0;
            sm[r] = 0.f;
        }
#pragma unroll
        for (int n = 0; n < 4; ++n)
#pragma unroll
            for (int r = 0; r < 4; ++r) {
                float p = exp2f((z[m][n][r] - mr[r]) * SC);
                z[m][n][r] = p;
                sm[r] += p;
            }
#pragma unroll
        for (int r = 0; r < 4; ++r) {
            float t = sm[r];
            t += __shfl_xor(t, 1);
            t += __shfl_xor(t, 2);
            t += __shfl_xor(t, 4);
            t += __shfl_xor(t, 8);
            sm[r] = 1.0f / t;
        }
#pragma unroll
        for (int n = 0; n < 4; ++n)
#pragma unroll
            for (int r = 0; r < 4; ++r)
                smem[(wr * 64 + m * 16 + (lgrp << 2) + r) * 136 + wc * 64 + n * 16 + lrow]
                    = f2bf(z[m][n][r] * sm[r]);
    }
    __syncthreads();

    // ---- coalesced P write: 8 iters x (16B/lane), rows of 128 bf16 ----
    unsigned short* pg = P + ((size_t)b * 1024 + qt * 128) * 4096 + (size_t)jt * 128;
#pragma unroll
    for (int it = 0; it < 8; ++it) {
        const int idx = it * 256 + tid;
        const int qrow = idx >> 4;
        const int k = idx & 15;
        *(bf16x8*)(pg + (size_t)qrow * 4096 + k * 8) = *(const bf16x8*)&smem[qrow * 136 + k * 8];
    }
}

// ---------------------------------------------------------------------------
// Phase B: partial[ks][b][c][q] = P·V over K-chunk ks (1024 wide). Tile
// 128q x 128c, 16 BK=64 steps, double-buffered. f16 partials, plain stores.
// ---------------------------------------------------------------------------
__global__ __launch_bounds__(256, 2) void ism_pv(
    const unsigned short* __restrict__ P,    // [4][1024][4096] bf16
    const unsigned short* __restrict__ Vt,   // [4][256][4096] bf16
    unsigned short* __restrict__ part)       // [4ks][4b][256c][1024q] f16
{
    __shared__ unsigned short smem[32768];   // 64 KB: 2x(A,B) stage | f16 tile [128][136]

    const int tid = threadIdx.x;
    const int wid = tid >> 6;
    const int lane = tid & 63;
    const int lrow = lane & 15;
    const int lgrp = lane >> 4;
    const int wr = wid >> 1;
    const int wc = wid & 1;

    const int blk = blockIdx.x;             // 256 = 8 xcd * 32
    const int xcd = blk & 7;
    const int b = xcd >> 1;
    const int sub = blk >> 3;               // 0..31
    const int qt = sub & 7;
    const int ct = (sub >> 3) & 1;
    const int ks = (sub >> 4) | ((xcd & 1) << 1);  // 0..3

    const unsigned short* ag = P + ((size_t)b * 1024 + qt * 128) * 4096 + (size_t)ks * 1024;
    const unsigned short* bg = Vt + ((size_t)b * 256 + ct * 128) * 4096 + (size_t)ks * 1024;

    const f32x4 fzero = {0.f, 0.f, 0.f, 0.f};
    f32x4 z[4][4];
#pragma unroll
    for (int m = 0; m < 4; ++m)
#pragma unroll
        for (int n = 0; n < 4; ++n) z[m][n] = fzero;

    stage_tile(ag, smem, 4096, 0, wid, lane);
    stage_tile(bg, smem + 16384, 4096, 0, wid, lane);
    __syncthreads();

#pragma unroll 1
    for (int s = 0; s < 16; ++s) {
        const int cur = s & 1;
        if (s < 15) {
            stage_tile(ag, smem + (cur ^ 1) * 8192, 4096, (s + 1) * 64, wid, lane);
            stage_tile(bg, smem + 16384 + (cur ^ 1) * 8192, 4096, (s + 1) * 64, wid, lane);
        }
        gemm_step(smem + cur * 8192 + wr * 4096, smem + 16384 + cur * 8192 + wc * 4096,
                  z, lrow, lgrp);
        __syncthreads();
    }

    // ---- dump f16 tile [128 c][136 q-pad] (4B packed q-pairs), coalesced out ----
#pragma unroll
    for (int m = 0; m < 4; ++m)
#pragma unroll
        for (int n = 0; n < 4; ++n) {
            const int c = wc * 64 + n * 16 + lrow;
            const int q = wr * 64 + m * 16 + (lgrp << 2);
            f16x2 h0 = {(f16)z[m][n][0], (f16)z[m][n][1]};
            f16x2 h1 = {(f16)z[m][n][2], (f16)z[m][n][3]};
            *(f16x2*)&smem[c * 136 + q] = h0;
            *(f16x2*)&smem[c * 136 + q + 2] = h1;
        }
    __syncthreads();

    unsigned short* pg = part + (((size_t)ks * 4 + b) * 256 + ct * 128) * 1024 + qt * 128;
#pragma unroll
    for (int it = 0; it < 8; ++it) {
        const int idx = it * 256 + tid;
        const int crow = idx >> 4;
        const int k = idx & 15;
        *(bf16x8*)(pg + (size_t)crow * 1024 + k * 8) = *(const bf16x8*)&smem[crow * 136 + k * 8];
    }
}

// ---------------------------------------------------------------------------
// Reduce: Z = sum_ks partial (f16) + D (exact f32), 2x2 upsample duplication.
// ---------------------------------------------------------------------------
__global__ __launch_bounds__(256) void ism_red(
    const unsigned short* __restrict__ part, const float* __restrict__ D,
    float* __restrict__ Z)
{
    const int blk = blockIdx.x;             // 2048 = 8 xcd * 256
    const int xcd = blk & 7;
    const int b = xcd >> 1;
    const int lin = (blk >> 3) * 256 + threadIdx.x;  // 0..65535
    const int q0 = (lin & 511) << 1;
    const int c = ((lin >> 9) & 127) | ((xcd & 1) << 7);

    float v0 = 0.f, v1 = 0.f;
#pragma unroll
    for (int ks = 0; ks < 4; ++ks) {
        f16x2 h = *(const f16x2*)&part[(((size_t)ks * 4 + b) * 256 + c) * 1024 + q0];
        v0 += (float)h[0];
        v1 += (float)h[1];
    }
    const size_t base = ((size_t)b * 256 + c) * 1024 + q0;
    f32x2 d = *(const f32x2*)(D + base);
    v0 += d[0];
    v1 += d[1];

    const int qh = q0 >> 5, qw = q0 & 31;
    float* o = Z + (((size_t)b * 256 + c) * 64 + qh * 2) * 64 + qw * 2;
    f32x4 val = {v0, v0, v1, v1};
    *(f32x4*)o = val;
    *(f32x4*)(o + 64) = val;
}

// ---------------------------------------------------------------------------
extern "C" void kernel_launch(void* const* d_in, const int* in_sizes, int n_in,
                              void* d_out, int out_size, void* d_ws, size_t ws_size,
                              hipStream_t stream)
{
    const float* D = (const float*)d_in[0];  // [4,256,32,32]
    const float* S = (const float*)d_in[1];  // [4,256,64,64]
    float* Z = (float*)d_out;

    // ws layout (50 MiB, proven available):
    //  [0,8M)    Kt [4][4096][256] bf16   } dead after ism_qk;
    //  [8,10M)   Qb [4][1024][256] bf16   } part (8.4 MB f16) overlays [0,8.4M)
    //  [10,42M)  P  [4][1024][4096] bf16
    //  [42,50M)  Vt [4][256][4096] bf16
    char* ws = (char*)d_ws;
    unsigned short* Kt = (unsigned short*)ws;
    unsigned short* Qb = (unsigned short*)(ws + 8388608);
    unsigned short* P  = (unsigned short*)(ws + 10485760);
    unsigned short* Vt = (unsigned short*)(ws + 44040192);
    unsigned short* part = (unsigned short*)ws;  // [4][4][256][1024] f16

    cvt_transpose<<<dim3(128, 8, 4), 256, 0, stream>>>(S, Kt, Vt, 4096);
    cvt_transpose<<<dim3(32, 8, 4), 256, 0, stream>>>(D, Qb, nullptr, 1024);

    ism_qk<<<1024, 256, 0, stream>>>(Kt, Qb, P);
    ism_pv<<<256, 256, 0, stream>>>(P, Vt, part);
    ism_red<<<2048, 256, 0, stream>>>(part, D, Z);
}